// Round 6
// baseline (243.172 us; speedup 1.0000x reference)
//
#include <hip/hip_runtime.h>

#define G_ 128
#define N_ 1024
#define E_ 64
#define I_ 128
#define H_ 128
#define O_ 128
#define EPSV 1e-5f

// workspace layout (float offsets)
#define WS_SPECIN  0                // [4][E][G][I] partials = 4194304 floats
#define WS_GRAM    4194304          // [4][G][E][E] partials = 2097152
#define WS_ROWSUM  6291456          // [4][G][E] = 32768
#define WS_SPECOUT 6324224          // [G][E][O] = 1048576
#define WS_STATS   7372800          // [256]: sum(h)[128], sum(h^2)[128]
#define WS_SCALE   7373056          // [256]: scale[128], shift[128]
// total = 7373312 floats = 29.5 MB

// ---------------------------------------------------------------------------
// K1: per (g, n-chunk of 256): spec_in[e,i] += eigen^T @ feature,
//     gram[e1,e2] += eigen^T @ eigen, rowsum[e] += eigen^T @ 1.
// grid (128, 4) = 512 blocks -> 2 blocks/CU (52 KB LDS each; 104 < 160 KB):
// one block's compute hides the other's staging (no double-buffer needed).
// Thread (h,tr,tc): h = t>>7 (n-half K-split), u = t&127, tr = u>>4 (e0=8tr),
// tc = u&15 (i slices 4tc and 64+4tc; gram e2 = 4tc; 8e x 8i = 64 acc/thread).
// rowsum folded into the e2 register reads (no extra LDS traffic).
// Halves merged through LDS (contiguous float4 layout, conflict-free).
// LDS intensity: 5 x b128 = 80 B per 100 FMA = 0.8 B/FMA (vs ~1.0 balance).
// ---------------------------------------------------------------------------
__global__ __launch_bounds__(256) void k1_project(
    const float* __restrict__ feature, const float* __restrict__ eigen,
    float* __restrict__ ws)
{
  __shared__ float eig_lds[64][64];    // 16 KB (reused as gram-partial buffer)
  __shared__ float feat_lds[64][128];  // 32 KB (reused as acc-partial buffer)
  __shared__ float rs_lds[1024];       // 4 KB rowsum partials [h*8+tr][64]
  const int g = blockIdx.x;
  const int s = blockIdx.y;
  const int t = threadIdx.x;
  const int h = t >> 7;
  const int u = t & 127;
  const int tr = u >> 4;
  const int tc = u & 15;

  const float4* esrc = (const float4*)(eigen + ((size_t)g * N_ + s * 256) * E_);
  const float4* fsrc = (const float4*)(feature + ((size_t)g * N_ + s * 256) * I_);
  float4* edst = (float4*)(&eig_lds[0][0]);
  float4* fdst = (float4*)(&feat_lds[0][0]);

  float acc[8][8];
  float gr[8][4];
  float rs4[4] = {0.f, 0.f, 0.f, 0.f};
#pragma unroll
  for (int a = 0; a < 8; ++a) {
#pragma unroll
    for (int b = 0; b < 8; ++b) acc[a][b] = 0.f;
#pragma unroll
    for (int b = 0; b < 4; ++b) gr[a][b] = 0.f;
  }

  for (int tile = 0; tile < 4; ++tile) {
    __syncthreads();
#pragma unroll
    for (int j = 0; j < 4; ++j) edst[j * 256 + t] = esrc[tile * 1024 + j * 256 + t];
#pragma unroll
    for (int j = 0; j < 8; ++j) fdst[j * 256 + t] = fsrc[tile * 2048 + j * 256 + t];
    __syncthreads();

    for (int n0 = 0; n0 < 32; ++n0) {
      const int n = h * 32 + n0;
      float4 ea = *(const float4*)&eig_lds[n][8 * tr];
      float4 eb = *(const float4*)&eig_lds[n][8 * tr + 4];
      float4 e2 = *(const float4*)&eig_lds[n][4 * tc];
      float4 fa = *(const float4*)&feat_lds[n][4 * tc];
      float4 fb = *(const float4*)&feat_lds[n][64 + 4 * tc];
      float ev[8] = {ea.x, ea.y, ea.z, ea.w, eb.x, eb.y, eb.z, eb.w};
      float fv[8] = {fa.x, fa.y, fa.z, fa.w, fb.x, fb.y, fb.z, fb.w};
      float e2v[4] = {e2.x, e2.y, e2.z, e2.w};
      rs4[0] += e2v[0]; rs4[1] += e2v[1]; rs4[2] += e2v[2]; rs4[3] += e2v[3];
#pragma unroll
      for (int a = 0; a < 8; ++a) {
#pragma unroll
        for (int b = 0; b < 8; ++b) acc[a][b] = fmaf(ev[a], fv[b], acc[a][b]);
#pragma unroll
        for (int b = 0; b < 4; ++b) gr[a][b] = fmaf(ev[a], e2v[b], gr[a][b]);
      }
    }
  }

  // ---- merge the two n-halves through LDS ----
  __syncthreads();  // all waves done reading tile data; safe to overwrite LDS
  *(float4*)&rs_lds[(h * 8 + tr) * 64 + 4 * tc] =
      make_float4(rs4[0], rs4[1], rs4[2], rs4[3]);
  float* pf = &feat_lds[0][0];  // 8192 floats: 16 chunks x 512
  float* pg = &eig_lds[0][0];   // 4096 floats: 8 chunks x 512
  if (h == 1) {
#pragma unroll
    for (int a = 0; a < 8; ++a) {
      *(float4*)&pf[(a * 2 + 0) * 512 + u * 4] =
          make_float4(acc[a][0], acc[a][1], acc[a][2], acc[a][3]);
      *(float4*)&pf[(a * 2 + 1) * 512 + u * 4] =
          make_float4(acc[a][4], acc[a][5], acc[a][6], acc[a][7]);
      *(float4*)&pg[a * 512 + u * 4] =
          make_float4(gr[a][0], gr[a][1], gr[a][2], gr[a][3]);
    }
  }
  __syncthreads();
  if (h == 0) {
#pragma unroll
    for (int a = 0; a < 8; ++a) {
      float4 p0 = *(const float4*)&pf[(a * 2 + 0) * 512 + u * 4];
      float4 p1 = *(const float4*)&pf[(a * 2 + 1) * 512 + u * 4];
      float4 pgv = *(const float4*)&pg[a * 512 + u * 4];
      acc[a][0] += p0.x; acc[a][1] += p0.y; acc[a][2] += p0.z; acc[a][3] += p0.w;
      acc[a][4] += p1.x; acc[a][5] += p1.y; acc[a][6] += p1.z; acc[a][7] += p1.w;
      gr[a][0] += pgv.x; gr[a][1] += pgv.y; gr[a][2] += pgv.z; gr[a][3] += pgv.w;
      const int e = 8 * tr + a;
      size_t sb = WS_SPECIN + ((size_t)(s * E_ + e) * G_ + g) * I_;
      *(float4*)&ws[sb + 4 * tc] =
          make_float4(acc[a][0], acc[a][1], acc[a][2], acc[a][3]);
      *(float4*)&ws[sb + 64 + 4 * tc] =
          make_float4(acc[a][4], acc[a][5], acc[a][6], acc[a][7]);
      size_t gb = WS_GRAM + ((size_t)(s * G_ + g) * E_ + e) * E_ + 4 * tc;
      *(float4*)&ws[gb] = make_float4(gr[a][0], gr[a][1], gr[a][2], gr[a][3]);
    }
  }
  if (t < 64) {
    // (h=0,tr=0) slot + (h=1,tr=0) slot; other tr slots are duplicates
    ws[WS_ROWSUM + (size_t)(s * G_ + g) * E_ + t] = rs_lds[t] + rs_lds[512 + t];
  }
}

// ---------------------------------------------------------------------------
// K2: per (e, 32-g chunk): hidden = relu(X @ W1[e] + b1), out = hidden @ W2[e] + b2
// grid (64, 4), block 256. X and H stored TRANSPOSED in LDS (XT[i][g], HT[k][g])
// so both GEMM operands are float4/broadcast reads (one-time conflicted
// transpose writes amortize against 2x128-iteration read loops).
// Thread (tg,tk)=(t>>5,t&31): g in {4tg..4tg+3}, k/o in {4tk..4tk+3}
// ---------------------------------------------------------------------------
__global__ __launch_bounds__(256) void k2_mlp(
    const float* __restrict__ w1, const float* __restrict__ b1,
    const float* __restrict__ w2, const float* __restrict__ b2,
    float* __restrict__ ws)
{
  __shared__ float Wl[128 * 128];  // 64 KB
  __shared__ float XT[128][32];    // 16 KB
  __shared__ float HT[128][32];    // 16 KB
  const int e = blockIdx.x;
  const int g0 = blockIdx.y * 32;
  const int t = threadIdx.x;
  const int tg = t >> 5;
  const int tk = t & 31;

  {
    const float4* wsrc = (const float4*)(w1 + (size_t)e * I_ * H_);
    float4* wdst = (float4*)Wl;
#pragma unroll
    for (int j = 0; j < 16; ++j) wdst[j * 256 + t] = wsrc[j * 256 + t];
  }
#pragma unroll
  for (int j = 0; j < 4; ++j) {
    int c = j * 256 + t;
    int gl = c >> 5;
    int i4 = (c & 31) * 4;
    size_t base = WS_SPECIN + ((size_t)e * G_ + g0 + gl) * I_ + i4;
    float4 v0 = *(const float4*)&ws[base];
    float4 v1 = *(const float4*)&ws[base + 1048576];
    float4 v2 = *(const float4*)&ws[base + 2097152];
    float4 v3 = *(const float4*)&ws[base + 3145728];
    XT[i4 + 0][gl] = v0.x + v1.x + v2.x + v3.x;
    XT[i4 + 1][gl] = v0.y + v1.y + v2.y + v3.y;
    XT[i4 + 2][gl] = v0.z + v1.z + v2.z + v3.z;
    XT[i4 + 3][gl] = v0.w + v1.w + v2.w + v3.w;
  }
  __syncthreads();

  {
    float4 bb = *(const float4*)&b1[e * H_ + 4 * tk];
    float h[4][4];
#pragma unroll
    for (int a = 0; a < 4; ++a) { h[a][0]=bb.x; h[a][1]=bb.y; h[a][2]=bb.z; h[a][3]=bb.w; }
    for (int i = 0; i < 128; ++i) {
      float4 xv = *(const float4*)&XT[i][4 * tg];
      float4 wr = *(const float4*)&Wl[i * 128 + 4 * tk];
      float xa[4] = {xv.x, xv.y, xv.z, xv.w};
      float wv[4] = {wr.x, wr.y, wr.z, wr.w};
#pragma unroll
      for (int a = 0; a < 4; ++a)
#pragma unroll
        for (int b = 0; b < 4; ++b) h[a][b] = fmaf(xa[a], wv[b], h[a][b]);
    }
#pragma unroll
    for (int a = 0; a < 4; ++a)
#pragma unroll
      for (int b = 0; b < 4; ++b)
        HT[4 * tk + b][4 * tg + a] = fmaxf(h[a][b], 0.f);
  }
  __syncthreads();
  {
    const float4* wsrc = (const float4*)(w2 + (size_t)e * H_ * O_);
    float4* wdst = (float4*)Wl;
#pragma unroll
    for (int j = 0; j < 16; ++j) wdst[j * 256 + t] = wsrc[j * 256 + t];
  }
  __syncthreads();
  {
    float4 bb = *(const float4*)&b2[e * O_ + 4 * tk];
    float o[4][4];
#pragma unroll
    for (int a = 0; a < 4; ++a) { o[a][0]=bb.x; o[a][1]=bb.y; o[a][2]=bb.z; o[a][3]=bb.w; }
    for (int k = 0; k < 128; ++k) {
      float4 hv = *(const float4*)&HT[k][4 * tg];
      float4 wr = *(const float4*)&Wl[k * 128 + 4 * tk];
      float ha[4] = {hv.x, hv.y, hv.z, hv.w};
      float wv[4] = {wr.x, wr.y, wr.z, wr.w};
#pragma unroll
      for (int a = 0; a < 4; ++a)
#pragma unroll
        for (int b = 0; b < 4; ++b) o[a][b] = fmaf(ha[a], wv[b], o[a][b]);
    }
#pragma unroll
    for (int a = 0; a < 4; ++a) {
      size_t ob = WS_SPECOUT + ((size_t)(g0 + 4 * tg + a) * E_ + e) * O_ + 4 * tk;
      *(float4*)&ws[ob] = make_float4(o[a][0], o[a][1], o[a][2], o[a][3]);
    }
  }
}

// ---------------------------------------------------------------------------
// K2b: GEMM-ified stats. grid (128 g, 2 o-halves), block 256.
// Y[e1][o] = sum_e2 G[e1][e2]*S[e2][o] with 4e x 4o register tiles
// (G symmetric: Gm[e2][e1-slice] float4 reads == G[e1-slice][e2]), then
// ssq_o = sum_e1 S[e1][o]*Y[e1][o], sm_o = sum_e1 S[e1][o]*R[e1],
// 16-way tr-reduction via LDS, one atomicAdd per (o, stat).
// ---------------------------------------------------------------------------
__global__ __launch_bounds__(256) void k2b_stats(float* __restrict__ ws)
{
  __shared__ float So[64][64];   // 16 KB  [e][o-local]
  __shared__ float Gm[64][64];   // 16 KB
  __shared__ float Rsh[64];
  __shared__ float RedM[16][64]; // 4 KB
  __shared__ float RedS[16][64]; // 4 KB
  const int g = blockIdx.x;
  const int oc = blockIdx.y;
  const int t = threadIdx.x;
  const int tr = t >> 4;
  const int tc = t & 15;

#pragma unroll
  for (int j = 0; j < 4; ++j) {
    int c = j * 256 + t;
    int e = c >> 4;
    int o4 = (c & 15) * 4;
    *(float4*)&So[e][o4] = *(const float4*)&ws[WS_SPECOUT + (size_t)g * E_ * O_ +
                                               (size_t)e * O_ + oc * 64 + o4];
  }
#pragma unroll
  for (int j = 0; j < 4; ++j) {
    int c = j * 256 + t;
    size_t base = WS_GRAM + (size_t)g * 4096 + (size_t)c * 4;
    float4 v0 = *(const float4*)&ws[base];
    float4 v1 = *(const float4*)&ws[base + 524288];
    float4 v2 = *(const float4*)&ws[base + 1048576];
    float4 v3 = *(const float4*)&ws[base + 1572864];
    float4 r;
    r.x = v0.x + v1.x + v2.x + v3.x;
    r.y = v0.y + v1.y + v2.y + v3.y;
    r.z = v0.z + v1.z + v2.z + v3.z;
    r.w = v0.w + v1.w + v2.w + v3.w;
    ((float4*)(&Gm[0][0]))[c] = r;
  }
  if (t < 64) {
    Rsh[t] = ws[WS_ROWSUM + (size_t)g * E_ + t]
           + ws[WS_ROWSUM + 8192 + (size_t)g * E_ + t]
           + ws[WS_ROWSUM + 16384 + (size_t)g * E_ + t]
           + ws[WS_ROWSUM + 24576 + (size_t)g * E_ + t];
  }
  __syncthreads();

  float y[4][4];
#pragma unroll
  for (int a = 0; a < 4; ++a)
#pragma unroll
    for (int b = 0; b < 4; ++b) y[a][b] = 0.f;

  for (int e2 = 0; e2 < 64; ++e2) {
    float4 gv = *(const float4*)&Gm[e2][4 * tr];  // = G[4tr..][e2] (symmetric)
    float4 sv = *(const float4*)&So[e2][4 * tc];
    float ga[4] = {gv.x, gv.y, gv.z, gv.w};
    float sb[4] = {sv.x, sv.y, sv.z, sv.w};
#pragma unroll
    for (int a = 0; a < 4; ++a)
#pragma unroll
      for (int b = 0; b < 4; ++b) y[a][b] = fmaf(ga[a], sb[b], y[a][b]);
  }

  float sp[4] = {0.f, 0.f, 0.f, 0.f};
  float sm[4] = {0.f, 0.f, 0.f, 0.f};
#pragma unroll
  for (int a = 0; a < 4; ++a) {
    const int e1 = 4 * tr + a;
    float4 sv = *(const float4*)&So[e1][4 * tc];
    float r = Rsh[e1];
    float sb[4] = {sv.x, sv.y, sv.z, sv.w};
#pragma unroll
    for (int b = 0; b < 4; ++b) {
      sp[b] = fmaf(sb[b], y[a][b], sp[b]);
      sm[b] = fmaf(sb[b], r, sm[b]);
    }
  }
  *(float4*)&RedS[tr][4 * tc] = make_float4(sp[0], sp[1], sp[2], sp[3]);
  *(float4*)&RedM[tr][4 * tc] = make_float4(sm[0], sm[1], sm[2], sm[3]);
  __syncthreads();
  if (t < 64) {
    float ssq = 0.f, smm = 0.f;
#pragma unroll
    for (int w = 0; w < 16; ++w) { ssq += RedS[w][t]; smm += RedM[w][t]; }
    atomicAdd(&ws[WS_STATS + oc * 64 + t], smm);
    atomicAdd(&ws[WS_STATS + 128 + oc * 64 + t], ssq);
  }
}

// ---------------------------------------------------------------------------
// K2c: finalize BN affine: scale = gamma*rsqrt(var+eps), shift = beta - mean*scale
// ---------------------------------------------------------------------------
__global__ void k2c_finalize(const float* __restrict__ gamma, const float* __restrict__ beta,
                             float* __restrict__ ws)
{
  const int t = threadIdx.x;
  if (t < 128) {
    const float inv = 1.f / (float)(G_ * N_);
    float mean = ws[WS_STATS + t] * inv;
    float var = fmaxf(ws[WS_STATS + 128 + t] * inv - mean * mean, 0.f);
    float sc = gamma[t] * rsqrtf(var + EPSV);
    ws[WS_SCALE + t] = sc;
    ws[WS_SCALE + 128 + t] = beta[t] - mean * sc;
  }
}

// ---------------------------------------------------------------------------
// K3: per (g, 64-row chunk): h = eigen[g] @ spec_out[g]; out = feature + relu(h*scale+shift)
// grid (128, 16), block 256. At HBM co-bound floor (~167 MB total traffic).
// Al padded to 68 to break stride-64 bank aliasing on broadcast reads.
// Note: blocks sharing spec_out[g] sit at indices g+128y; 128%8==0 so they all
// land on the same XCD under round-robin — panel L2 locality already optimal.
// ---------------------------------------------------------------------------
__global__ __launch_bounds__(256) void k3_output(
    const float* __restrict__ feature, const float* __restrict__ eigen,
    const float* __restrict__ ws, float* __restrict__ out)
{
  __shared__ float Al[64][68];   // padded
  __shared__ float Bl[64][128];
  const int g = blockIdx.x;
  const int nb = blockIdx.y * 64;
  const int t = threadIdx.x;
  const int tr = t >> 4;
  const int tc = t & 15;

  {
    const float4* asrc = (const float4*)(eigen + ((size_t)g * N_ + nb) * E_);
#pragma unroll
    for (int j = 0; j < 4; ++j) {
      int c = j * 256 + t;
      *(float4*)&Al[c >> 4][(c & 15) * 4] = asrc[c];
    }
    const float4* bsrc = (const float4*)(ws + WS_SPECOUT + (size_t)g * E_ * O_);
    float4* bdst = (float4*)(&Bl[0][0]);
#pragma unroll
    for (int j = 0; j < 8; ++j) bdst[j * 256 + t] = bsrc[j * 256 + t];
  }
  __syncthreads();

  float acc[4][8];
#pragma unroll
  for (int a = 0; a < 4; ++a)
#pragma unroll
    for (int b = 0; b < 8; ++b) acc[a][b] = 0.f;

  for (int kq = 0; kq < 16; ++kq) {
    const int k0 = 4 * kq;
    float4 a0 = *(const float4*)&Al[tr][k0];
    float4 a1 = *(const float4*)&Al[16 + tr][k0];
    float4 a2 = *(const float4*)&Al[32 + tr][k0];
    float4 a3 = *(const float4*)&Al[48 + tr][k0];
    float am[4][4] = {{a0.x, a0.y, a0.z, a0.w},
                      {a1.x, a1.y, a1.z, a1.w},
                      {a2.x, a2.y, a2.z, a2.w},
                      {a3.x, a3.y, a3.z, a3.w}};
#pragma unroll
    for (int kk = 0; kk < 4; ++kk) {
      float4 bx = *(const float4*)&Bl[k0 + kk][4 * tc];
      float4 by = *(const float4*)&Bl[k0 + kk][64 + 4 * tc];
#pragma unroll
      for (int r = 0; r < 4; ++r) {
        float av = am[r][kk];
        acc[r][0] = fmaf(av, bx.x, acc[r][0]);
        acc[r][1] = fmaf(av, bx.y, acc[r][1]);
        acc[r][2] = fmaf(av, bx.z, acc[r][2]);
        acc[r][3] = fmaf(av, bx.w, acc[r][3]);
        acc[r][4] = fmaf(av, by.x, acc[r][4]);
        acc[r][5] = fmaf(av, by.y, acc[r][5]);
        acc[r][6] = fmaf(av, by.z, acc[r][6]);
        acc[r][7] = fmaf(av, by.w, acc[r][7]);
      }
    }
  }

  float4 sca = *(const float4*)&ws[WS_SCALE + 4 * tc];
  float4 scb = *(const float4*)&ws[WS_SCALE + 64 + 4 * tc];
  float4 sha = *(const float4*)&ws[WS_SCALE + 128 + 4 * tc];
  float4 shb = *(const float4*)&ws[WS_SCALE + 128 + 64 + 4 * tc];
#pragma unroll
  for (int r = 0; r < 4; ++r) {
    const size_t row = (size_t)g * N_ + nb + 16 * r + tr;
    const float* fp = feature + row * I_;
    float* op = out + row * O_;
    float4 f1 = *(const float4*)&fp[4 * tc];
    float4 f2 = *(const float4*)&fp[64 + 4 * tc];
    float4 o1, o2;
    o1.x = f1.x + fmaxf(fmaf(acc[r][0], sca.x, sha.x), 0.f);
    o1.y = f1.y + fmaxf(fmaf(acc[r][1], sca.y, sha.y), 0.f);
    o1.z = f1.z + fmaxf(fmaf(acc[r][2], sca.z, sha.z), 0.f);
    o1.w = f1.w + fmaxf(fmaf(acc[r][3], sca.w, sha.w), 0.f);
    o2.x = f2.x + fmaxf(fmaf(acc[r][4], scb.x, shb.x), 0.f);
    o2.y = f2.y + fmaxf(fmaf(acc[r][5], scb.y, shb.y), 0.f);
    o2.z = f2.z + fmaxf(fmaf(acc[r][6], scb.z, shb.z), 0.f);
    o2.w = f2.w + fmaxf(fmaf(acc[r][7], scb.w, shb.w), 0.f);
    *(float4*)&op[4 * tc] = o1;
    *(float4*)&op[64 + 4 * tc] = o2;
  }
}

extern "C" void kernel_launch(void* const* d_in, const int* in_sizes, int n_in,
                              void* d_out, int out_size, void* d_ws, size_t ws_size,
                              hipStream_t stream) {
  (void)in_sizes; (void)n_in; (void)out_size; (void)ws_size;
  const float* feature = (const float*)d_in[0];
  const float* eigen   = (const float*)d_in[1];
  const float* w1      = (const float*)d_in[2];
  const float* b1      = (const float*)d_in[3];
  const float* w2      = (const float*)d_in[4];
  const float* b2      = (const float*)d_in[5];
  const float* gamma   = (const float*)d_in[6];
  const float* beta    = (const float*)d_in[7];
  float* out = (float*)d_out;
  float* ws  = (float*)d_ws;

  hipMemsetAsync(ws + WS_STATS, 0, 256 * sizeof(float), stream);
  k1_project<<<dim3(G_, 4), 256, 0, stream>>>(feature, eigen, ws);
  k2_mlp<<<dim3(E_, 4), 256, 0, stream>>>(w1, b1, w2, b2, ws);
  k2b_stats<<<dim3(G_, 2), 256, 0, stream>>>(ws);
  k2c_finalize<<<1, 128, 0, stream>>>(gamma, beta, ws);
  k3_output<<<dim3(G_, N_ / 64), 256, 0, stream>>>(feature, eigen, ws, out);
}

// Round 7
// 229.067 us; speedup vs baseline: 1.0616x; 1.0616x over previous
//
#include <hip/hip_runtime.h>

#define G_ 128
#define N_ 1024
#define E_ 64
#define I_ 128
#define H_ 128
#define O_ 128
#define EPSV 1e-5f

// workspace layout (float offsets)
#define WS_SPECIN  0                // [4][E][G][I] partials = 4194304 floats
#define WS_GRAM    4194304          // [4][G][E][E] partials = 2097152
#define WS_ROWSUM  6291456          // [4][G][E] = 32768
#define WS_SPECOUT 6324224          // [G][E][O] = 1048576
#define WS_STATS   7372800          // [256]: sum(h)[128], sum(h^2)[128]
#define WS_SCALE   7373056          // [256]: scale[128], shift[128]
// total = 7373312 floats = 29.5 MB

typedef __attribute__((ext_vector_type(4))) float f32x4;
typedef __attribute__((ext_vector_type(8))) short bf16x8;
#define MFMA16(a, b, c) __builtin_amdgcn_mfma_f32_16x16x32_bf16((a), (b), (c), 0, 0, 0)

// round-to-nearest-even bf16 (upper 16 bits returned in low half)
__device__ __forceinline__ unsigned bf16_rne(float x) {
  unsigned u = __float_as_uint(x);
  return (u + 0x7fffu + ((u >> 16) & 1u)) >> 16;
}
// split a,b into bf16 hi/lo pairs packed as [a|b<<16]; x ~= hi + lo to ~2^-17 rel
__device__ __forceinline__ void split2(float a, float b, unsigned& hi, unsigned& lo) {
  unsigned ha = bf16_rne(a), hb = bf16_rne(b);
  float ra = a - __uint_as_float(ha << 16);
  float rb = b - __uint_as_float(hb << 16);
  hi = ha | (hb << 16);
  lo = bf16_rne(ra) | (bf16_rne(rb) << 16);
}

// ---------------------------------------------------------------------------
// K1 (MFMA bf16-split): per (g, s-chunk of 256 n):
//   [spec_in | gram](64e x 192col) = Eigen^T (64x256) @ [Feature | Eigen] (256x192)
// via mfma_f32_16x16x32_bf16, 3 products per tile (hi*hi + hi*lo + lo*hi).
// Output layout/partials byte-identical to the fp32 version (K2/K2b unchanged).
// LDS: transposed bf16 hi/lo tiles for one 64-n K-chunk, NT=72 pad,
// n-blocks XOR-swizzled by (row>>3)&7 on BOTH write and frag-read.
// rowsum accumulated from the fp32 staging loads (exact, as before).
// grid (128,4), block 256, LDS 55 KB -> 2 blocks/CU.
// ---------------------------------------------------------------------------
__global__ __launch_bounds__(256) void k1_project(
    const float* __restrict__ feature, const float* __restrict__ eigen,
    float* __restrict__ ws)
{
  __shared__ short ET[2][64][72];   // [hi/lo][e][n]  18 KB
  __shared__ short FT[2][128][72];  // [hi/lo][i][n]  36 KB
  __shared__ float rs_lds[4][64];   // 1 KB

  const int g = blockIdx.x;
  const int s = blockIdx.y;
  const int t = threadIdx.x;
  const int l = t & 63;
  const int w = t >> 6;        // wave 0..3
  const int lm = l & 15;       // MFMA row/col lane index
  const int lk = l >> 4;       // MFMA k-group 0..3
  const size_t nglob = (size_t)g * N_ + (size_t)s * 256;

  // staging thread mappings (coalesced 256B row reads)
  const int se = t & 63;       // eigen: e lane
  const int sng = t >> 6;      // eigen: n-group 0..3
  const int si = t & 127;      // feature: i lane
  const int smg = t >> 7;      // feature: n-group 0..1

  f32x4 acc[4][3];
#pragma unroll
  for (int m = 0; m < 4; ++m)
#pragma unroll
    for (int c = 0; c < 3; ++c) acc[m][c] = (f32x4){0.f, 0.f, 0.f, 0.f};

  float rs = 0.f;

  for (int ch = 0; ch < 4; ++ch) {
    __syncthreads();  // previous chunk's frag reads done before overwrite
    const int nb = ch * 64;

    // ---- stage eigen -> ET (transpose + split), swizzled n-blocks ----
    const float* eg = eigen + (nglob + nb) * E_ + se;
#pragma unroll
    for (int p = 0; p < 4; ++p) {
      const int nl = p * 16 + sng * 4;
      float x0 = eg[(size_t)(nl + 0) * E_];
      float x1 = eg[(size_t)(nl + 1) * E_];
      float x2 = eg[(size_t)(nl + 2) * E_];
      float x3 = eg[(size_t)(nl + 3) * E_];
      rs += x0 + x1 + x2 + x3;
      unsigned h01, l01, h23, l23;
      split2(x0, x1, h01, l01);
      split2(x2, x3, h23, l23);
      const int cb = (((nl >> 3) ^ (se >> 3)) << 3) | (nl & 7);
      *(uint2*)&ET[0][se][cb] = make_uint2(h01, h23);
      *(uint2*)&ET[1][se][cb] = make_uint2(l01, l23);
    }
    // ---- stage feature -> FT (transpose + split), swizzled n-blocks ----
    const float* fg = feature + (nglob + nb) * I_ + si;
#pragma unroll
    for (int p = 0; p < 8; ++p) {
      const int nl = p * 8 + smg * 4;
      float x0 = fg[(size_t)(nl + 0) * I_];
      float x1 = fg[(size_t)(nl + 1) * I_];
      float x2 = fg[(size_t)(nl + 2) * I_];
      float x3 = fg[(size_t)(nl + 3) * I_];
      unsigned h01, l01, h23, l23;
      split2(x0, x1, h01, l01);
      split2(x2, x3, h23, l23);
      const int cb = (((nl >> 3) ^ ((si >> 3) & 7)) << 3) | (nl & 7);
      *(uint2*)&FT[0][si][cb] = make_uint2(h01, h23);
      *(uint2*)&FT[1][si][cb] = make_uint2(l01, l23);
    }
    __syncthreads();

    // ---- MFMA: wave w owns col-tiles {w, w+4, w+8}, all 4 e-tiles ----
#pragma unroll
    for (int kt = 0; kt < 2; ++kt) {
      bf16x8 ah[4], al[4];
#pragma unroll
      for (int m = 0; m < 4; ++m) {
        const int er = m * 16 + lm;
        const int cc = (((kt * 4 + lk) ^ (er >> 3)) << 3);
        ah[m] = *(const bf16x8*)&ET[0][er][cc];
        al[m] = *(const bf16x8*)&ET[1][er][cc];
      }
#pragma unroll
      for (int cl = 0; cl < 3; ++cl) {
        const int ct = w + cl * 4;                   // wave-uniform
        const short(*Bh)[72] = (ct < 8) ? FT[0] : ET[0];
        const short(*Bl)[72] = (ct < 8) ? FT[1] : ET[1];
        const int br = ((ct < 8) ? ct : (ct - 8)) * 16 + lm;
        const int cc = (((kt * 4 + lk) ^ ((br >> 3) & 7)) << 3);
        bf16x8 bh = *(const bf16x8*)&Bh[br][cc];
        bf16x8 bl = *(const bf16x8*)&Bl[br][cc];
#pragma unroll
        for (int m = 0; m < 4; ++m) {
          acc[m][cl] = MFMA16(ah[m], bh, acc[m][cl]);
          acc[m][cl] = MFMA16(ah[m], bl, acc[m][cl]);
          acc[m][cl] = MFMA16(al[m], bh, acc[m][cl]);
        }
      }
    }
  }

  // ---- epilogue: D mapping col=lane&15, row=(lane>>4)*4+r (measured m89/m91) ----
#pragma unroll
  for (int cl = 0; cl < 3; ++cl) {
    const int ct = w + cl * 4;
#pragma unroll
    for (int m = 0; m < 4; ++m) {
#pragma unroll
      for (int r = 0; r < 4; ++r) {
        const int e = m * 16 + lk * 4 + r;
        const float v = acc[m][cl][r];
        if (ct < 8) {
          const int i = ct * 16 + lm;
          ws[WS_SPECIN + ((size_t)(s * E_ + e) * G_ + g) * I_ + i] = v;
        } else {
          const int e2 = (ct - 8) * 16 + lm;
          ws[WS_GRAM + ((size_t)(s * G_ + g) * E_ + e) * E_ + e2] = v;
        }
      }
    }
  }
  rs_lds[sng][se] = rs;
  __syncthreads();
  if (t < 64) {
    ws[WS_ROWSUM + (size_t)(s * G_ + g) * E_ + t] =
        rs_lds[0][t] + rs_lds[1][t] + rs_lds[2][t] + rs_lds[3][t];
  }
}

// ---------------------------------------------------------------------------
// K2: per (e, 32-g chunk): hidden = relu(X @ W1[e] + b1), out = hidden @ W2[e] + b2
// (unchanged from measured-passing round-6 version)
// ---------------------------------------------------------------------------
__global__ __launch_bounds__(256) void k2_mlp(
    const float* __restrict__ w1, const float* __restrict__ b1,
    const float* __restrict__ w2, const float* __restrict__ b2,
    float* __restrict__ ws)
{
  __shared__ float Wl[128 * 128];  // 64 KB
  __shared__ float XT[128][32];    // 16 KB
  __shared__ float HT[128][32];    // 16 KB
  const int e = blockIdx.x;
  const int g0 = blockIdx.y * 32;
  const int t = threadIdx.x;
  const int tg = t >> 5;
  const int tk = t & 31;

  {
    const float4* wsrc = (const float4*)(w1 + (size_t)e * I_ * H_);
    float4* wdst = (float4*)Wl;
#pragma unroll
    for (int j = 0; j < 16; ++j) wdst[j * 256 + t] = wsrc[j * 256 + t];
  }
#pragma unroll
  for (int j = 0; j < 4; ++j) {
    int c = j * 256 + t;
    int gl = c >> 5;
    int i4 = (c & 31) * 4;
    size_t base = WS_SPECIN + ((size_t)e * G_ + g0 + gl) * I_ + i4;
    float4 v0 = *(const float4*)&ws[base];
    float4 v1 = *(const float4*)&ws[base + 1048576];
    float4 v2 = *(const float4*)&ws[base + 2097152];
    float4 v3 = *(const float4*)&ws[base + 3145728];
    XT[i4 + 0][gl] = v0.x + v1.x + v2.x + v3.x;
    XT[i4 + 1][gl] = v0.y + v1.y + v2.y + v3.y;
    XT[i4 + 2][gl] = v0.z + v1.z + v2.z + v3.z;
    XT[i4 + 3][gl] = v0.w + v1.w + v2.w + v3.w;
  }
  __syncthreads();

  {
    float4 bb = *(const float4*)&b1[e * H_ + 4 * tk];
    float h[4][4];
#pragma unroll
    for (int a = 0; a < 4; ++a) { h[a][0]=bb.x; h[a][1]=bb.y; h[a][2]=bb.z; h[a][3]=bb.w; }
    for (int i = 0; i < 128; ++i) {
      float4 xv = *(const float4*)&XT[i][4 * tg];
      float4 wr = *(const float4*)&Wl[i * 128 + 4 * tk];
      float xa[4] = {xv.x, xv.y, xv.z, xv.w};
      float wv[4] = {wr.x, wr.y, wr.z, wr.w};
#pragma unroll
      for (int a = 0; a < 4; ++a)
#pragma unroll
        for (int b = 0; b < 4; ++b) h[a][b] = fmaf(xa[a], wv[b], h[a][b]);
    }
#pragma unroll
    for (int a = 0; a < 4; ++a)
#pragma unroll
      for (int b = 0; b < 4; ++b)
        HT[4 * tk + b][4 * tg + a] = fmaxf(h[a][b], 0.f);
  }
  __syncthreads();
  {
    const float4* wsrc = (const float4*)(w2 + (size_t)e * H_ * O_);
    float4* wdst = (float4*)Wl;
#pragma unroll
    for (int j = 0; j < 16; ++j) wdst[j * 256 + t] = wsrc[j * 256 + t];
  }
  __syncthreads();
  {
    float4 bb = *(const float4*)&b2[e * O_ + 4 * tk];
    float o[4][4];
#pragma unroll
    for (int a = 0; a < 4; ++a) { o[a][0]=bb.x; o[a][1]=bb.y; o[a][2]=bb.z; o[a][3]=bb.w; }
    for (int k = 0; k < 128; ++k) {
      float4 hv = *(const float4*)&HT[k][4 * tg];
      float4 wr = *(const float4*)&Wl[k * 128 + 4 * tk];
      float ha[4] = {hv.x, hv.y, hv.z, hv.w};
      float wv[4] = {wr.x, wr.y, wr.z, wr.w};
#pragma unroll
      for (int a = 0; a < 4; ++a)
#pragma unroll
        for (int b = 0; b < 4; ++b) o[a][b] = fmaf(ha[a], wv[b], o[a][b]);
    }
#pragma unroll
    for (int a = 0; a < 4; ++a) {
      size_t ob = WS_SPECOUT + ((size_t)(g0 + 4 * tg + a) * E_ + e) * O_ + 4 * tk;
      *(float4*)&ws[ob] = make_float4(o[a][0], o[a][1], o[a][2], o[a][3]);
    }
  }
}

// ---------------------------------------------------------------------------
// K2b: GEMM-ified stats (unchanged from measured-passing round-6 version)
// ---------------------------------------------------------------------------
__global__ __launch_bounds__(256) void k2b_stats(float* __restrict__ ws)
{
  __shared__ float So[64][64];
  __shared__ float Gm[64][64];
  __shared__ float Rsh[64];
  __shared__ float RedM[16][64];
  __shared__ float RedS[16][64];
  const int g = blockIdx.x;
  const int oc = blockIdx.y;
  const int t = threadIdx.x;
  const int tr = t >> 4;
  const int tc = t & 15;

#pragma unroll
  for (int j = 0; j < 4; ++j) {
    int c = j * 256 + t;
    int e = c >> 4;
    int o4 = (c & 15) * 4;
    *(float4*)&So[e][o4] = *(const float4*)&ws[WS_SPECOUT + (size_t)g * E_ * O_ +
                                               (size_t)e * O_ + oc * 64 + o4];
  }
#pragma unroll
  for (int j = 0; j < 4; ++j) {
    int c = j * 256 + t;
    size_t base = WS_GRAM + (size_t)g * 4096 + (size_t)c * 4;
    float4 v0 = *(const float4*)&ws[base];
    float4 v1 = *(const float4*)&ws[base + 524288];
    float4 v2 = *(const float4*)&ws[base + 1048576];
    float4 v3 = *(const float4*)&ws[base + 1572864];
    float4 r;
    r.x = v0.x + v1.x + v2.x + v3.x;
    r.y = v0.y + v1.y + v2.y + v3.y;
    r.z = v0.z + v1.z + v2.z + v3.z;
    r.w = v0.w + v1.w + v2.w + v3.w;
    ((float4*)(&Gm[0][0]))[c] = r;
  }
  if (t < 64) {
    Rsh[t] = ws[WS_ROWSUM + (size_t)g * E_ + t]
           + ws[WS_ROWSUM + 8192 + (size_t)g * E_ + t]
           + ws[WS_ROWSUM + 16384 + (size_t)g * E_ + t]
           + ws[WS_ROWSUM + 24576 + (size_t)g * E_ + t];
  }
  __syncthreads();

  float y[4][4];
#pragma unroll
  for (int a = 0; a < 4; ++a)
#pragma unroll
    for (int b = 0; b < 4; ++b) y[a][b] = 0.f;

  for (int e2 = 0; e2 < 64; ++e2) {
    float4 gv = *(const float4*)&Gm[e2][4 * tr];
    float4 sv = *(const float4*)&So[e2][4 * tc];
    float ga[4] = {gv.x, gv.y, gv.z, gv.w};
    float sb[4] = {sv.x, sv.y, sv.z, sv.w};
#pragma unroll
    for (int a = 0; a < 4; ++a)
#pragma unroll
      for (int b = 0; b < 4; ++b) y[a][b] = fmaf(ga[a], sb[b], y[a][b]);
  }

  float sp[4] = {0.f, 0.f, 0.f, 0.f};
  float sm[4] = {0.f, 0.f, 0.f, 0.f};
#pragma unroll
  for (int a = 0; a < 4; ++a) {
    const int e1 = 4 * tr + a;
    float4 sv = *(const float4*)&So[e1][4 * tc];
    float r = Rsh[e1];
    float sb[4] = {sv.x, sv.y, sv.z, sv.w};
#pragma unroll
    for (int b = 0; b < 4; ++b) {
      sp[b] = fmaf(sb[b], y[a][b], sp[b]);
      sm[b] = fmaf(sb[b], r, sm[b]);
    }
  }
  *(float4*)&RedS[tr][4 * tc] = make_float4(sp[0], sp[1], sp[2], sp[3]);
  *(float4*)&RedM[tr][4 * tc] = make_float4(sm[0], sm[1], sm[2], sm[3]);
  __syncthreads();
  if (t < 64) {
    float ssq = 0.f, smm = 0.f;
#pragma unroll
    for (int wv = 0; wv < 16; ++wv) { ssq += RedS[wv][t]; smm += RedM[wv][t]; }
    atomicAdd(&ws[WS_STATS + oc * 64 + t], smm);
    atomicAdd(&ws[WS_STATS + 128 + oc * 64 + t], ssq);
  }
}

// ---------------------------------------------------------------------------
// K2c: finalize BN affine (unchanged)
// ---------------------------------------------------------------------------
__global__ void k2c_finalize(const float* __restrict__ gamma, const float* __restrict__ beta,
                             float* __restrict__ ws)
{
  const int t = threadIdx.x;
  if (t < 128) {
    const float inv = 1.f / (float)(G_ * N_);
    float mean = ws[WS_STATS + t] * inv;
    float var = fmaxf(ws[WS_STATS + 128 + t] * inv - mean * mean, 0.f);
    float sc = gamma[t] * rsqrtf(var + EPSV);
    ws[WS_SCALE + t] = sc;
    ws[WS_SCALE + 128 + t] = beta[t] - mean * sc;
  }
}

// ---------------------------------------------------------------------------
// K3: fused output GEMM + BN + relu + residual (unchanged from round-6)
// ---------------------------------------------------------------------------
__global__ __launch_bounds__(256) void k3_output(
    const float* __restrict__ feature, const float* __restrict__ eigen,
    const float* __restrict__ ws, float* __restrict__ out)
{
  __shared__ float Al[64][68];
  __shared__ float Bl[64][128];
  const int g = blockIdx.x;
  const int nb = blockIdx.y * 64;
  const int t = threadIdx.x;
  const int tr = t >> 4;
  const int tc = t & 15;

  {
    const float4* asrc = (const float4*)(eigen + ((size_t)g * N_ + nb) * E_);
#pragma unroll
    for (int j = 0; j < 4; ++j) {
      int c = j * 256 + t;
      *(float4*)&Al[c >> 4][(c & 15) * 4] = asrc[c];
    }
    const float4* bsrc = (const float4*)(ws + WS_SPECOUT + (size_t)g * E_ * O_);
    float4* bdst = (float4*)(&Bl[0][0]);
#pragma unroll
    for (int j = 0; j < 8; ++j) bdst[j * 256 + t] = bsrc[j * 256 + t];
  }
  __syncthreads();

  float acc[4][8];
#pragma unroll
  for (int a = 0; a < 4; ++a)
#pragma unroll
    for (int b = 0; b < 8; ++b) acc[a][b] = 0.f;

  for (int kq = 0; kq < 16; ++kq) {
    const int k0 = 4 * kq;
    float4 a0 = *(const float4*)&Al[tr][k0];
    float4 a1 = *(const float4*)&Al[16 + tr][k0];
    float4 a2 = *(const float4*)&Al[32 + tr][k0];
    float4 a3 = *(const float4*)&Al[48 + tr][k0];
    float am[4][4] = {{a0.x, a0.y, a0.z, a0.w},
                      {a1.x, a1.y, a1.z, a1.w},
                      {a2.x, a2.y, a2.z, a2.w},
                      {a3.x, a3.y, a3.z, a3.w}};
#pragma unroll
    for (int kk = 0; kk < 4; ++kk) {
      float4 bx = *(const float4*)&Bl[k0 + kk][4 * tc];
      float4 by = *(const float4*)&Bl[k0 + kk][64 + 4 * tc];
#pragma unroll
      for (int r = 0; r < 4; ++r) {
        float av = am[r][kk];
        acc[r][0] = fmaf(av, bx.x, acc[r][0]);
        acc[r][1] = fmaf(av, bx.y, acc[r][1]);
        acc[r][2] = fmaf(av, bx.z, acc[r][2]);
        acc[r][3] = fmaf(av, bx.w, acc[r][3]);
        acc[r][4] = fmaf(av, by.x, acc[r][4]);
        acc[r][5] = fmaf(av, by.y, acc[r][5]);
        acc[r][6] = fmaf(av, by.z, acc[r][6]);
        acc[r][7] = fmaf(av, by.w, acc[r][7]);
      }
    }
  }

  float4 sca = *(const float4*)&ws[WS_SCALE + 4 * tc];
  float4 scb = *(const float4*)&ws[WS_SCALE + 64 + 4 * tc];
  float4 sha = *(const float4*)&ws[WS_SCALE + 128 + 4 * tc];
  float4 shb = *(const float4*)&ws[WS_SCALE + 128 + 64 + 4 * tc];
#pragma unroll
  for (int r = 0; r < 4; ++r) {
    const size_t row = (size_t)g * N_ + nb + 16 * r + tr;
    const float* fp = feature + row * I_;
    float* op = out + row * O_;
    float4 f1 = *(const float4*)&fp[4 * tc];
    float4 f2 = *(const float4*)&fp[64 + 4 * tc];
    float4 o1, o2;
    o1.x = f1.x + fmaxf(fmaf(acc[r][0], sca.x, sha.x), 0.f);
    o1.y = f1.y + fmaxf(fmaf(acc[r][1], sca.y, sha.y), 0.f);
    o1.z = f1.z + fmaxf(fmaf(acc[r][2], sca.z, sha.z), 0.f);
    o1.w = f1.w + fmaxf(fmaf(acc[r][3], sca.w, sha.w), 0.f);
    o2.x = f2.x + fmaxf(fmaf(acc[r][4], scb.x, shb.x), 0.f);
    o2.y = f2.y + fmaxf(fmaf(acc[r][5], scb.y, shb.y), 0.f);
    o2.z = f2.z + fmaxf(fmaf(acc[r][6], scb.z, shb.z), 0.f);
    o2.w = f2.w + fmaxf(fmaf(acc[r][7], scb.w, shb.w), 0.f);
    *(float4*)&op[4 * tc] = o1;
    *(float4*)&op[64 + 4 * tc] = o2;
  }
}

extern "C" void kernel_launch(void* const* d_in, const int* in_sizes, int n_in,
                              void* d_out, int out_size, void* d_ws, size_t ws_size,
                              hipStream_t stream) {
  (void)in_sizes; (void)n_in; (void)out_size; (void)ws_size;
  const float* feature = (const float*)d_in[0];
  const float* eigen   = (const float*)d_in[1];
  const float* w1      = (const float*)d_in[2];
  const float* b1      = (const float*)d_in[3];
  const float* w2      = (const float*)d_in[4];
  const float* b2      = (const float*)d_in[5];
  const float* gamma   = (const float*)d_in[6];
  const float* beta    = (const float*)d_in[7];
  float* out = (float*)d_out;
  float* ws  = (float*)d_ws;

  hipMemsetAsync(ws + WS_STATS, 0, 256 * sizeof(float), stream);
  k1_project<<<dim3(G_, 4), 256, 0, stream>>>(feature, eigen, ws);
  k2_mlp<<<dim3(E_, 4), 256, 0, stream>>>(w1, b1, w2, b2, ws);
  k2b_stats<<<dim3(G_, 2), 256, 0, stream>>>(ws);
  k2c_finalize<<<1, 128, 0, stream>>>(gamma, beta, ws);
  k3_output<<<dim3(G_, N_ / 64), 256, 0, stream>>>(feature, eigen, ws, out);
}

// Round 9
// 224.099 us; speedup vs baseline: 1.0851x; 1.0222x over previous
//
#include <hip/hip_runtime.h>

#define G_ 128
#define N_ 1024
#define E_ 64
#define I_ 128
#define H_ 128
#define O_ 128
#define EPSV 1e-5f

// workspace layout (float offsets)
#define WS_SPECIN  0                // [4][E][G][I] partials = 4194304 floats
#define WS_GRAM    4194304          // [4][G][E][E] partials = 2097152
#define WS_ROWSUM  6291456          // [4][G][E] = 32768
#define WS_SPECOUT 6324224          // [G][E][O] = 1048576
#define WS_STATS   7372800          // [256]: sum(h)[128], sum(h^2)[128]
#define WS_SCALE   7373056          // [256]: scale[128], shift[128]
// total = 7373312 floats = 29.5 MB

typedef __attribute__((ext_vector_type(4))) float f32x4;
typedef __attribute__((ext_vector_type(8))) short bf16x8;
#define MFMA16(a, b, c) __builtin_amdgcn_mfma_f32_16x16x32_bf16((a), (b), (c), 0, 0, 0)

__device__ __forceinline__ unsigned bf16_rne(float x) {
  unsigned u = __float_as_uint(x);
  return (u + 0x7fffu + ((u >> 16) & 1u)) >> 16;
}
__device__ __forceinline__ void split2(float a, float b, unsigned& hi, unsigned& lo) {
  unsigned ha = bf16_rne(a), hb = bf16_rne(b);
  float ra = a - __uint_as_float(ha << 16);
  float rb = b - __uint_as_float(hb << 16);
  hi = ha | (hb << 16);
  lo = bf16_rne(ra) | (bf16_rne(rb) << 16);
}

// ---------------------------------------------------------------------------
// K1 (MFMA bf16-split, col-split for occupancy): grid (128, 4, 2), block 256.
// cb = blockIdx.z: cb0 computes spec_in cols 0..63 AND gram (B = FT | ET);
// cb1 computes spec_in cols 64..127. LDS 37 KB -> 4 blocks/CU (2x round-7).
// Outputs byte-identical to round-7 (K2/K2b readers unchanged).
// ---------------------------------------------------------------------------
__global__ __launch_bounds__(256) void k1_project(
    const float* __restrict__ feature, const float* __restrict__ eigen,
    float* __restrict__ ws)
{
  __shared__ short ET[2][64][72];   // [hi/lo][e][n]  18 KB
  __shared__ short FT[2][64][72];   // [hi/lo][i-half][n]  18 KB
  __shared__ float rs_lds[4][64];   // 1 KB

  const int g = blockIdx.x;
  const int s = blockIdx.y;
  const int cb = blockIdx.z;
  const int t = threadIdx.x;
  const int l = t & 63;
  const int w = t >> 6;
  const int lm = l & 15;
  const int lk = l >> 4;
  const size_t nglob = (size_t)g * N_ + (size_t)s * 256;

  const int se = t & 63;
  const int sng = t >> 6;

  f32x4 acc[4][2];
#pragma unroll
  for (int m = 0; m < 4; ++m) {
    acc[m][0] = (f32x4){0.f, 0.f, 0.f, 0.f};
    acc[m][1] = (f32x4){0.f, 0.f, 0.f, 0.f};
  }
  float rs = 0.f;

  for (int ch = 0; ch < 4; ++ch) {
    __syncthreads();
    const int nb = ch * 64;

    // ---- stage eigen -> ET (transpose + split), swizzled n-blocks ----
    const float* eg = eigen + (nglob + nb) * E_ + se;
#pragma unroll
    for (int p = 0; p < 4; ++p) {
      const int nl = p * 16 + sng * 4;
      float x0 = eg[(size_t)(nl + 0) * E_];
      float x1 = eg[(size_t)(nl + 1) * E_];
      float x2 = eg[(size_t)(nl + 2) * E_];
      float x3 = eg[(size_t)(nl + 3) * E_];
      rs += x0 + x1 + x2 + x3;
      unsigned h01, l01, h23, l23;
      split2(x0, x1, h01, l01);
      split2(x2, x3, h23, l23);
      const int cc = (((nl >> 3) ^ (se >> 3)) << 3) | (nl & 7);
      *(uint2*)&ET[0][se][cc] = make_uint2(h01, h23);
      *(uint2*)&ET[1][se][cc] = make_uint2(l01, l23);
    }
    // ---- stage feature half -> FT ----
    const float* fg = feature + (nglob + nb) * I_ + cb * 64 + se;
#pragma unroll
    for (int p = 0; p < 4; ++p) {
      const int nl = p * 16 + sng * 4;
      float x0 = fg[(size_t)(nl + 0) * I_];
      float x1 = fg[(size_t)(nl + 1) * I_];
      float x2 = fg[(size_t)(nl + 2) * I_];
      float x3 = fg[(size_t)(nl + 3) * I_];
      unsigned h01, l01, h23, l23;
      split2(x0, x1, h01, l01);
      split2(x2, x3, h23, l23);
      const int cc = (((nl >> 3) ^ (se >> 3)) << 3) | (nl & 7);
      *(uint2*)&FT[0][se][cc] = make_uint2(h01, h23);
      *(uint2*)&FT[1][se][cc] = make_uint2(l01, l23);
    }
    __syncthreads();

#pragma unroll
    for (int kt = 0; kt < 2; ++kt) {
      bf16x8 ah[4], al[4];
#pragma unroll
      for (int m = 0; m < 4; ++m) {
        const int er = m * 16 + lm;
        const int cc = (((kt * 4 + lk) ^ (er >> 3)) << 3);
        ah[m] = *(const bf16x8*)&ET[0][er][cc];
        al[m] = *(const bf16x8*)&ET[1][er][cc];
      }
      const int br = w * 16 + lm;
      const int cc = (((kt * 4 + lk) ^ (br >> 3)) << 3);
      {
        bf16x8 bh = *(const bf16x8*)&FT[0][br][cc];
        bf16x8 bl = *(const bf16x8*)&FT[1][br][cc];
#pragma unroll
        for (int m = 0; m < 4; ++m) {
          acc[m][0] = MFMA16(ah[m], bh, acc[m][0]);
          acc[m][0] = MFMA16(ah[m], bl, acc[m][0]);
          acc[m][0] = MFMA16(al[m], bh, acc[m][0]);
        }
      }
      if (cb == 0) {
        bf16x8 bh = *(const bf16x8*)&ET[0][br][cc];
        bf16x8 bl = *(const bf16x8*)&ET[1][br][cc];
#pragma unroll
        for (int m = 0; m < 4; ++m) {
          acc[m][1] = MFMA16(ah[m], bh, acc[m][1]);
          acc[m][1] = MFMA16(ah[m], bl, acc[m][1]);
          acc[m][1] = MFMA16(al[m], bh, acc[m][1]);
        }
      }
    }
  }

  // ---- epilogue: D map col=lane&15, row=(lane>>4)*4+r (HW-verified r7) ----
#pragma unroll
  for (int m = 0; m < 4; ++m) {
#pragma unroll
    for (int r = 0; r < 4; ++r) {
      const int e = m * 16 + lk * 4 + r;
      const int i = cb * 64 + w * 16 + lm;
      ws[WS_SPECIN + ((size_t)(s * E_ + e) * G_ + g) * I_ + i] = acc[m][0][r];
      if (cb == 0) {
        const int e2 = w * 16 + lm;
        ws[WS_GRAM + ((size_t)(s * G_ + g) * E_ + e) * E_ + e2] = acc[m][1][r];
      }
    }
  }
  if (cb == 0) {
    rs_lds[sng][se] = rs;
    __syncthreads();
    if (t < 64) {
      ws[WS_ROWSUM + (size_t)(s * G_ + g) * E_ + t] =
          rs_lds[0][t] + rs_lds[1][t] + rs_lds[2][t] + rs_lds[3][t];
    }
  }
}

// ---------------------------------------------------------------------------
// K2 (restructured for occupancy): grid (64 e, 8 g-chunks of 16), block 256.
// No W staging (round-7 used 96 KB LDS -> 1 block/CU): W rows stream from
// L2 as float4 per k-iteration. LDS = XT/HT panels only (17-pad, 17 KB).
// Thread (tg,tk) = (t>>5, t&31): g in {2tg, 2tg+1}, k/o in {4tk..4tk+3}.
// ---------------------------------------------------------------------------
__global__ __launch_bounds__(256) void k2_mlp(
    const float* __restrict__ w1, const float* __restrict__ b1,
    const float* __restrict__ w2, const float* __restrict__ b2,
    float* __restrict__ ws)
{
  __shared__ float XT[128][17];  // [i][g-local]
  __shared__ float HT[128][17];  // [k][g-local]
  const int e = blockIdx.x;
  const int g0 = blockIdx.y * 16;
  const int t = threadIdx.x;
  const int tg = t >> 5;
  const int tk = t & 31;

#pragma unroll
  for (int j = 0; j < 2; ++j) {
    int idx = j * 256 + t;
    int gl = idx >> 5;
    int i4 = (idx & 31) * 4;
    size_t base = WS_SPECIN + ((size_t)e * G_ + g0 + gl) * I_ + i4;
    float4 v0 = *(const float4*)&ws[base];
    float4 v1 = *(const float4*)&ws[base + 1048576];
    float4 v2 = *(const float4*)&ws[base + 2097152];
    float4 v3 = *(const float4*)&ws[base + 3145728];
    XT[i4 + 0][gl] = v0.x + v1.x + v2.x + v3.x;
    XT[i4 + 1][gl] = v0.y + v1.y + v2.y + v3.y;
    XT[i4 + 2][gl] = v0.z + v1.z + v2.z + v3.z;
    XT[i4 + 3][gl] = v0.w + v1.w + v2.w + v3.w;
  }
  __syncthreads();

  {
    const float* w1e = w1 + (size_t)e * I_ * H_;
    float4 bb = *(const float4*)&b1[e * H_ + 4 * tk];
    float h[2][4];
#pragma unroll
    for (int a = 0; a < 2; ++a) { h[a][0]=bb.x; h[a][1]=bb.y; h[a][2]=bb.z; h[a][3]=bb.w; }
    for (int i = 0; i < 128; ++i) {
      float4 wr = *(const float4*)&w1e[(size_t)i * H_ + 4 * tk];
      float xa0 = XT[i][2 * tg];
      float xa1 = XT[i][2 * tg + 1];
      h[0][0] = fmaf(xa0, wr.x, h[0][0]);
      h[0][1] = fmaf(xa0, wr.y, h[0][1]);
      h[0][2] = fmaf(xa0, wr.z, h[0][2]);
      h[0][3] = fmaf(xa0, wr.w, h[0][3]);
      h[1][0] = fmaf(xa1, wr.x, h[1][0]);
      h[1][1] = fmaf(xa1, wr.y, h[1][1]);
      h[1][2] = fmaf(xa1, wr.z, h[1][2]);
      h[1][3] = fmaf(xa1, wr.w, h[1][3]);
    }
#pragma unroll
    for (int a = 0; a < 2; ++a)
#pragma unroll
      for (int b = 0; b < 4; ++b)
        HT[4 * tk + b][2 * tg + a] = fmaxf(h[a][b], 0.f);
  }
  __syncthreads();
  {
    const float* w2e = w2 + (size_t)e * H_ * O_;
    float4 bb = *(const float4*)&b2[e * O_ + 4 * tk];
    float o[2][4];
#pragma unroll
    for (int a = 0; a < 2; ++a) { o[a][0]=bb.x; o[a][1]=bb.y; o[a][2]=bb.z; o[a][3]=bb.w; }
    for (int k = 0; k < 128; ++k) {
      float4 wr = *(const float4*)&w2e[(size_t)k * O_ + 4 * tk];
      float ha0 = HT[k][2 * tg];
      float ha1 = HT[k][2 * tg + 1];
      o[0][0] = fmaf(ha0, wr.x, o[0][0]);
      o[0][1] = fmaf(ha0, wr.y, o[0][1]);
      o[0][2] = fmaf(ha0, wr.z, o[0][2]);
      o[0][3] = fmaf(ha0, wr.w, o[0][3]);
      o[1][0] = fmaf(ha1, wr.x, o[1][0]);
      o[1][1] = fmaf(ha1, wr.y, o[1][1]);
      o[1][2] = fmaf(ha1, wr.z, o[1][2]);
      o[1][3] = fmaf(ha1, wr.w, o[1][3]);
    }
#pragma unroll
    for (int a = 0; a < 2; ++a) {
      size_t ob = WS_SPECOUT + ((size_t)(g0 + 2 * tg + a) * E_ + e) * O_ + 4 * tk;
      *(float4*)&ws[ob] = make_float4(o[a][0], o[a][1], o[a][2], o[a][3]);
    }
  }
}

// ---------------------------------------------------------------------------
// K2b: GEMM-ified stats. grid (128 g, 2 o-halves), block 256.
// FIX vs round-8 draft: restored the oc*64 offset on the stats atomics
// (dropping it sent o=64..127 stats into o=0..63 and left 64..127 zero).
// ---------------------------------------------------------------------------
__global__ __launch_bounds__(256) void k2b_stats(float* __restrict__ ws)
{
  __shared__ float So[64][64];
  __shared__ float Gm[64][64];
  __shared__ float Rsh[64];
  __shared__ float RedM[16][64];
  __shared__ float RedS[16][64];
  const int g = blockIdx.x;
  const int oc = blockIdx.y;
  const int t = threadIdx.x;
  const int tr = t >> 4;
  const int tc = t & 15;

#pragma unroll
  for (int j = 0; j < 4; ++j) {
    int c = j * 256 + t;
    int e = c >> 4;
    int o4 = (c & 15) * 4;
    *(float4*)&So[e][o4] = *(const float4*)&ws[WS_SPECOUT + (size_t)g * E_ * O_ +
                                               (size_t)e * O_ + oc * 64 + o4];
  }
#pragma unroll
  for (int j = 0; j < 4; ++j) {
    int c = j * 256 + t;
    size_t base = WS_GRAM + (size_t)g * 4096 + (size_t)c * 4;
    float4 v0 = *(const float4*)&ws[base];
    float4 v1 = *(const float4*)&ws[base + 524288];
    float4 v2 = *(const float4*)&ws[base + 1048576];
    float4 v3 = *(const float4*)&ws[base + 1572864];
    float4 r;
    r.x = v0.x + v1.x + v2.x + v3.x;
    r.y = v0.y + v1.y + v2.y + v3.y;
    r.z = v0.z + v1.z + v2.z + v3.z;
    r.w = v0.w + v1.w + v2.w + v3.w;
    ((float4*)(&Gm[0][0]))[c] = r;
  }
  if (t < 64) {
    Rsh[t] = ws[WS_ROWSUM + (size_t)g * E_ + t]
           + ws[WS_ROWSUM + 8192 + (size_t)g * E_ + t]
           + ws[WS_ROWSUM + 16384 + (size_t)g * E_ + t]
           + ws[WS_ROWSUM + 24576 + (size_t)g * E_ + t];
  }
  __syncthreads();

  float y[4][4];
#pragma unroll
  for (int a = 0; a < 4; ++a)
#pragma unroll
    for (int b = 0; b < 4; ++b) y[a][b] = 0.f;

  for (int e2 = 0; e2 < 64; ++e2) {
    float4 gv = *(const float4*)&Gm[e2][4 * tr];
    float4 sv = *(const float4*)&So[e2][4 * tc];
    float ga[4] = {gv.x, gv.y, gv.z, gv.w};
    float sb[4] = {sv.x, sv.y, sv.z, sv.w};
#pragma unroll
    for (int a = 0; a < 4; ++a)
#pragma unroll
      for (int b = 0; b < 4; ++b) y[a][b] = fmaf(ga[a], sb[b], y[a][b]);
  }

  float sp[4] = {0.f, 0.f, 0.f, 0.f};
  float sm[4] = {0.f, 0.f, 0.f, 0.f};
#pragma unroll
  for (int a = 0; a < 4; ++a) {
    const int e1 = 4 * tr + a;
    float4 sv = *(const float4*)&So[e1][4 * tc];
    float r = Rsh[e1];
    float sb[4] = {sv.x, sv.y, sv.z, sv.w};
#pragma unroll
    for (int b = 0; b < 4; ++b) {
      sp[b] = fmaf(sb[b], y[a][b], sp[b]);
      sm[b] = fmaf(sb[b], r, sm[b]);
    }
  }
  *(float4*)&RedS[tr][4 * tc] = make_float4(sp[0], sp[1], sp[2], sp[3]);
  *(float4*)&RedM[tr][4 * tc] = make_float4(sm[0], sm[1], sm[2], sm[3]);
  __syncthreads();
  if (t < 64) {
    float ssq = 0.f, smm = 0.f;
#pragma unroll
    for (int wv = 0; wv < 16; ++wv) { ssq += RedS[wv][t]; smm += RedM[wv][t]; }
    atomicAdd(&ws[WS_STATS + oc * 64 + t], smm);
    atomicAdd(&ws[WS_STATS + 128 + oc * 64 + t], ssq);
  }
}

// ---------------------------------------------------------------------------
// K2c: finalize BN affine (unchanged)
// ---------------------------------------------------------------------------
__global__ void k2c_finalize(const float* __restrict__ gamma, const float* __restrict__ beta,
                             float* __restrict__ ws)
{
  const int t = threadIdx.x;
  if (t < 128) {
    const float inv = 1.f / (float)(G_ * N_);
    float mean = ws[WS_STATS + t] * inv;
    float var = fmaxf(ws[WS_STATS + 128 + t] * inv - mean * mean, 0.f);
    float sc = gamma[t] * rsqrtf(var + EPSV);
    ws[WS_SCALE + t] = sc;
    ws[WS_SCALE + 128 + t] = beta[t] - mean * sc;
  }
}

// ---------------------------------------------------------------------------
// K3 (MFMA bf16-split): per (g, 128-row chunk): h = eigen @ spec_out,
// out = feature + relu(h*scale+shift). grid (128, 8), block 256 (4 waves).
// A = eigen[n][e]: k-contiguous, NO transpose; staged hi/lo bf16 with T2
// XOR-swizzle (write and read, same involution). B = spec_out in REGISTERS
// (8 frags/wave, built once from strided global reads). One barrier total.
// LDS 32 KB -> 3-4 blocks/CU.
// ---------------------------------------------------------------------------
__global__ __launch_bounds__(256) void k3_output(
    const float* __restrict__ feature, const float* __restrict__ eigen,
    const float* __restrict__ ws, float* __restrict__ out)
{
  __shared__ short AL[2][128][64];  // [hi/lo][n][e]  32 KB
  const int g = blockIdx.x;
  const int nb = blockIdx.y * 128;
  const int t = threadIdx.x;
  const int l = t & 63;
  const int w = t >> 6;
  const int lm = l & 15;
  const int lk = l >> 4;

  char* A0 = (char*)&AL[0][0][0];
  char* A1 = (char*)&AL[1][0][0];

  // ---- stage A (eigen rows, coalesced float4; split; swizzled write) ----
  {
    const float* eg = eigen + ((size_t)g * N_ + nb) * E_;
#pragma unroll
    for (int j = 0; j < 8; ++j) {
      int idx = j * 256 + t;
      int n = idx >> 4;
      int e4 = (idx & 15) * 4;
      float4 v = *(const float4*)&eg[(size_t)n * E_ + e4];
      unsigned h01, l01, h23, l23;
      split2(v.x, v.y, h01, l01);
      split2(v.z, v.w, h23, l23);
      int off = (n * 128 + e4 * 2) ^ ((n & 7) << 4);
      *(uint2*)(A0 + off) = make_uint2(h01, h23);
      *(uint2*)(A1 + off) = make_uint2(l01, l23);
    }
  }

  // ---- B fragments in registers + BN scale/shift ----
  bf16x8 bh[2][2], bl[2][2];
  float sc[2], sh[2];
  {
    const float* so = ws + WS_SPECOUT + (size_t)g * E_ * O_;
#pragma unroll
    for (int oti = 0; oti < 2; ++oti) {
      const int o = (2 * w + oti) * 16 + lm;
      sc[oti] = ws[WS_SCALE + o];
      sh[oti] = ws[WS_SCALE + 128 + o];
#pragma unroll
      for (int kt = 0; kt < 2; ++kt) {
#pragma unroll
        for (int j = 0; j < 8; ++j) {
          float x = so[(size_t)(kt * 32 + lk * 8 + j) * O_ + o];
          unsigned hb = bf16_rne(x);
          float r = x - __uint_as_float(hb << 16);
          bh[oti][kt][j] = (short)hb;
          bl[oti][kt][j] = (short)bf16_rne(r);
        }
      }
    }
  }
  __syncthreads();

  f32x4 acc[8][2];
#pragma unroll
  for (int nt = 0; nt < 8; ++nt) {
    acc[nt][0] = (f32x4){0.f, 0.f, 0.f, 0.f};
    acc[nt][1] = (f32x4){0.f, 0.f, 0.f, 0.f};
  }

#pragma unroll
  for (int kt = 0; kt < 2; ++kt) {
#pragma unroll
    for (int nt = 0; nt < 8; ++nt) {
      const int n = nt * 16 + lm;
      const int off = (n * 128 + kt * 64 + lk * 16) ^ ((n & 7) << 4);
      bf16x8 ah = *(const bf16x8*)(A0 + off);
      bf16x8 al2 = *(const bf16x8*)(A1 + off);
#pragma unroll
      for (int oti = 0; oti < 2; ++oti) {
        acc[nt][oti] = MFMA16(ah, bh[oti][kt], acc[nt][oti]);
        acc[nt][oti] = MFMA16(ah, bl[oti][kt], acc[nt][oti]);
        acc[nt][oti] = MFMA16(al2, bh[oti][kt], acc[nt][oti]);
      }
    }
  }

  // ---- fused epilogue: BN affine + relu + residual ----
#pragma unroll
  for (int nt = 0; nt < 8; ++nt) {
#pragma unroll
    for (int oti = 0; oti < 2; ++oti) {
      const int o = (2 * w + oti) * 16 + lm;
#pragma unroll
      for (int r = 0; r < 4; ++r) {
        const size_t grow = (size_t)g * N_ + nb + nt * 16 + lk * 4 + r;
        float hv = fmaxf(fmaf(acc[nt][oti][r], sc[oti], sh[oti]), 0.f);
        out[grow * O_ + o] = feature[grow * I_ + o] + hv;
      }
    }
  }
}

extern "C" void kernel_launch(void* const* d_in, const int* in_sizes, int n_in,
                              void* d_out, int out_size, void* d_ws, size_t ws_size,
                              hipStream_t stream) {
  (void)in_sizes; (void)n_in; (void)out_size; (void)ws_size;
  const float* feature = (const float*)d_in[0];
  const float* eigen   = (const float*)d_in[1];
  const float* w1      = (const float*)d_in[2];
  const float* b1      = (const float*)d_in[3];
  const float* w2      = (const float*)d_in[4];
  const float* b2      = (const float*)d_in[5];
  const float* gamma   = (const float*)d_in[6];
  const float* beta    = (const float*)d_in[7];
  float* out = (float*)d_out;
  float* ws  = (float*)d_ws;

  hipMemsetAsync(ws + WS_STATS, 0, 256 * sizeof(float), stream);
  k1_project<<<dim3(G_, 4, 2), 256, 0, stream>>>(feature, eigen, ws);
  k2_mlp<<<dim3(E_, 8), 256, 0, stream>>>(w1, b1, w2, b2, ws);
  k2b_stats<<<dim3(G_, 2), 256, 0, stream>>>(ws);
  k2c_finalize<<<1, 128, 0, stream>>>(gamma, beta, ws);
  k3_output<<<dim3(G_, N_ / 128), 256, 0, stream>>>(feature, eigen, ws, out);
}